// Round 22
// baseline (714.121 us; speedup 1.0000x reference)
//
#include <hip/hip_runtime.h>
#include <math.h>

#define NB 32
#define L  1024
#define CH 512                 // timesteps per chunk
#define NCH (L / CH)           // 2 chunks
#define RC (NB * CH)           // 16384 rows per chunk
#define DM 256
#define DI 512
#define DS 16
#define SCT 32                 // sub-chunk timesteps (scan)
#define NSC (CH / SCT)         // 16 sub-chunks
#define LOG2E 1.44269504f
#define LN2   0.69314718f

typedef short short8 __attribute__((ext_vector_type(8)));
typedef float f32x4 __attribute__((ext_vector_type(4)));
typedef float f32x2 __attribute__((ext_vector_type(2)));
typedef unsigned short u16;

// bf16 split helpers: x ~= hi + lo, both bf16 (rne).
__device__ inline unsigned f2bf_u(float x) {
    unsigned u = __float_as_uint(x);
    return (u + 0x7fffu + ((u >> 16) & 1u)) >> 16;
}

// Layout: per-chunk activations use (t_local, b, feat): row r = t_local*32 + b.

// ---------------------------------------------------------------------------
// p1 (K=4) + bias + LayerNorm; emits bf16 hi/lo PLANES for MFMA in_proj.
// ---------------------------------------------------------------------------
__global__ __launch_bounds__(256) void k_p1_ln(
    const float* __restrict__ xseq, const float* __restrict__ w,
    const float* __restrict__ bias, const float* __restrict__ g,
    const float* __restrict__ bb, u16* __restrict__ outh, u16* __restrict__ outl,
    int t0)
{
    int r  = blockIdx.x;
    int b  = r & 31;
    int tl = r >> 5;
    int m  = threadIdx.x;
    const float* xr = xseq + ((size_t)b * L + t0 + tl) * 4;
    float x0 = xr[0], x1 = xr[1], x2 = xr[2], x3 = xr[3];
    const float* wr = w + m * 4;
    float v = bias[m] + x0 * wr[0] + x1 * wr[1] + x2 * wr[2] + x3 * wr[3];

    __shared__ float s1[4], s2[4];
    float a = v, bq = v * v;
    for (int o = 32; o > 0; o >>= 1) { a += __shfl_down(a, o); bq += __shfl_down(bq, o); }
    int wid = m >> 6, lane = m & 63;
    if (lane == 0) { s1[wid] = a; s2[wid] = bq; }
    __syncthreads();
    if (m == 0) {
        s1[0] = s1[0] + s1[1] + s1[2] + s1[3];
        s2[0] = s2[0] + s2[1] + s2[2] + s2[3];
    }
    __syncthreads();
    float mu  = s1[0] * (1.f / 256.f);
    float var = s2[0] * (1.f / 256.f) - mu * mu;
    float o2 = (v - mu) * rsqrtf(var + 1e-5f) * g[m] + bb[m];
    unsigned hb = f2bf_u(o2);
    outh[(size_t)r * 256 + m] = (u16)hb;
    outl[(size_t)r * 256 + m] = (u16)f2bf_u(o2 - __uint_as_float(hb << 16));
}

// ---------------------------------------------------------------------------
// LayerNorm over 256; fp32 in, bf16 hi/lo planes out.
// ---------------------------------------------------------------------------
__global__ __launch_bounds__(256) void k_ln(
    const float* __restrict__ in, const float* __restrict__ g,
    const float* __restrict__ bb, u16* __restrict__ outh, u16* __restrict__ outl)
{
    int r = blockIdx.x;
    int m = threadIdx.x;
    float v = in[(size_t)r * 256 + m];

    __shared__ float s1[4], s2[4];
    float a = v, bq = v * v;
    for (int o = 32; o > 0; o >>= 1) { a += __shfl_down(a, o); bq += __shfl_down(bq, o); }
    int wid = m >> 6, lane = m & 63;
    if (lane == 0) { s1[wid] = a; s2[wid] = bq; }
    __syncthreads();
    if (m == 0) {
        s1[0] = s1[0] + s1[1] + s1[2] + s1[3];
        s2[0] = s2[0] + s2[1] + s2[2] + s2[3];
    }
    __syncthreads();
    float mu  = s1[0] * (1.f / 256.f);
    float var = s2[0] * (1.f / 256.f) - mu * mu;
    float o2 = (v - mu) * rsqrtf(var + 1e-5f) * g[m] + bb[m];
    unsigned hb = f2bf_u(o2);
    outh[(size_t)r * 256 + m] = (u16)hb;
    outl[(size_t)r * 256 + m] = (u16)f2bf_u(o2 - __uint_as_float(hb << 16));
}

// ---------------------------------------------------------------------------
// in_proj weight conversion (2 matrices) -> hi/lo planes, 1 launch.
// ---------------------------------------------------------------------------
__global__ __launch_bounds__(256) void k_wcvt2(
    const float* __restrict__ w1i, const float* __restrict__ w2i,
    u16* __restrict__ o1h, u16* __restrict__ o1l,
    u16* __restrict__ o2h, u16* __restrict__ o2l)
{
    int i = blockIdx.x * 256 + threadIdx.x;     // 524288, grid 2048
    const float* src; u16 *oh, *ol; int j;
    if (i < 262144) { src = w1i; oh = o1h; ol = o1l; j = i; }
    else            { src = w2i; oh = o2h; ol = o2l; j = i - 262144; }
    float v = src[j];
    unsigned hb = f2bf_u(v);
    oh[j] = (u16)hb;
    ol[j] = (u16)f2bf_u(v - __uint_as_float(hb << 16));
}

// ---------------------------------------------------------------------------
// combined weight Wc = Wp2 @ Wo1  ([256,256]x[256,512] -> [256,512]),
// packed to hi/lo planes.  (y@Wo1^T)@Wp2^T + b == y@Wc^T + b  (exact algebra)
// ---------------------------------------------------------------------------
__global__ __launch_bounds__(256) void k_wcomb(
    const float* __restrict__ p2w, const float* __restrict__ outw,
    u16* __restrict__ och, u16* __restrict__ ocl)
{
    int idx = blockIdx.x * 256 + threadIdx.x;   // 131072, grid 512
    int n = idx >> 9, k = idx & 511;
    const float* pr = p2w + n * 256;
    float s = 0.f;
    for (int j = 0; j < 256; j++)
        s = fmaf(pr[j], outw[(size_t)j * 512 + k], s);
    unsigned hb = f2bf_u(s);
    och[idx] = (u16)hb;
    ocl[idx] = (u16)f2bf_u(s - __uint_as_float(hb << 16));
}

// ---------------------------------------------------------------------------
// split-bf16 MFMA GEMM (3-term): C[M,N] = A[M,K]*W[N,K]^T (+bias).
// A,W as separate hi/lo bf16 planes. 128x128 tile, BK=32. fp32 output.
// ---------------------------------------------------------------------------
template <bool BIAS>
__global__ __launch_bounds__(256) void k_gmfma(
    const u16* __restrict__ Ahg, const u16* __restrict__ Alg, int lda,
    const u16* __restrict__ Whg, const u16* __restrict__ Wlg,
    const float* __restrict__ bias, float* __restrict__ C0,
    int N, int K)
{
    __shared__ u16 Ah[128 * 40], Al[128 * 40];
    __shared__ u16 Wh[128 * 40], Wl[128 * 40];

    int tid = threadIdx.x;
    int wv = tid >> 6, ln = tid & 63;
    int wr = wv >> 1, wc = wv & 1;
    int m0 = blockIdx.x * 128, n0 = blockIdx.y * 128;
    int sr = tid >> 1, sk = (tid & 1) << 4;
    int frow = ln & 15, fk = (ln >> 4) << 3;

    f32x4 acc[4][4] = {};

    for (int k0 = 0; k0 < K; k0 += 32) {
        const u16* ah = Ahg + (size_t)(m0 + sr) * lda + k0 + sk;
        const u16* al = Alg + (size_t)(m0 + sr) * lda + k0 + sk;
        const u16* wh = Whg + (size_t)(n0 + sr) * K + k0 + sk;
        const u16* wl = Wlg + (size_t)(n0 + sr) * K + k0 + sk;
        short8 vah0 = *(const short8*)ah, vah1 = *(const short8*)(ah + 8);
        short8 val0 = *(const short8*)al, val1 = *(const short8*)(al + 8);
        short8 vwh0 = *(const short8*)wh, vwh1 = *(const short8*)(wh + 8);
        short8 vwl0 = *(const short8*)wl, vwl1 = *(const short8*)(wl + 8);

        __syncthreads();   // previous iteration's frag reads done

        *(short8*)&Ah[sr * 40 + sk]     = vah0;
        *(short8*)&Ah[sr * 40 + sk + 8] = vah1;
        *(short8*)&Al[sr * 40 + sk]     = val0;
        *(short8*)&Al[sr * 40 + sk + 8] = val1;
        *(short8*)&Wh[sr * 40 + sk]     = vwh0;
        *(short8*)&Wh[sr * 40 + sk + 8] = vwh1;
        *(short8*)&Wl[sr * 40 + sk]     = vwl0;
        *(short8*)&Wl[sr * 40 + sk + 8] = vwl1;

        __syncthreads();

        short8 afh[4], afl[4], wfh[4], wfl[4];
#pragma unroll
        for (int g = 0; g < 4; g++) {
            int ra = (wr * 64 + g * 16 + frow) * 40 + fk;
            int rw = (wc * 64 + g * 16 + frow) * 40 + fk;
            afh[g] = *(const short8*)&Ah[ra];
            afl[g] = *(const short8*)&Al[ra];
            wfh[g] = *(const short8*)&Wh[rw];
            wfl[g] = *(const short8*)&Wl[rw];
        }
#pragma unroll
        for (int mg = 0; mg < 4; mg++)
#pragma unroll
            for (int ng = 0; ng < 4; ng++) {
                acc[mg][ng] = __builtin_amdgcn_mfma_f32_16x16x32_bf16(afh[mg], wfh[ng], acc[mg][ng], 0, 0, 0);
                acc[mg][ng] = __builtin_amdgcn_mfma_f32_16x16x32_bf16(afh[mg], wfl[ng], acc[mg][ng], 0, 0, 0);
                acc[mg][ng] = __builtin_amdgcn_mfma_f32_16x16x32_bf16(afl[mg], wfh[ng], acc[mg][ng], 0, 0, 0);
            }
    }

    // C layout: col=lane&15, row=(lane>>4)*4+reg  [verified m89]
#pragma unroll
    for (int ng = 0; ng < 4; ng++) {
        int col = n0 + wc * 64 + ng * 16 + frow;
        float bv = BIAS ? bias[col] : 0.f;
#pragma unroll
        for (int mg = 0; mg < 4; mg++)
#pragma unroll
            for (int r = 0; r < 4; r++) {
                int row = m0 + wr * 64 + mg * 16 + (ln >> 4) * 4 + r;
                C0[(size_t)row * N + col] = acc[mg][ng][r] + bv;
            }
    }
}

// ---------------------------------------------------------------------------
// xproj K-split partial GEMM: Cpart[slice][M][48] = A[:, ks..ks+128) * W^T.
// grid (M/64, 4). Reduced to dbc by k_dbr (deterministic order).
// ---------------------------------------------------------------------------
__global__ __launch_bounds__(256) void k_xpart(
    const float* __restrict__ A, const float* __restrict__ W,
    float* __restrict__ Cpart, int M, int K, int kcnt)
{
    const int BM = 64, BK = 16;
    __shared__ float As[BK][BM];
    __shared__ float Ws[BK][64];

    int m0   = blockIdx.x * BM;
    int kbeg = blockIdx.y * kcnt;
    int tid = threadIdx.x;
    int tx  = tid & 15, ty = tid >> 4;
    int lr  = tid >> 2;
    int lc  = (tid & 3) * 4;

    float acc[4][4] = {};

    for (int k0 = kbeg; k0 < kbeg + kcnt; k0 += BK) {
        float4 av = *(const float4*)(A + (size_t)(m0 + lr) * K + k0 + lc);
        As[lc + 0][lr] = av.x; As[lc + 1][lr] = av.y;
        As[lc + 2][lr] = av.z; As[lc + 3][lr] = av.w;
        float4 wv = make_float4(0.f, 0.f, 0.f, 0.f);
        if (lr < 48) wv = *(const float4*)(W + (size_t)lr * K + k0 + lc);
        Ws[lc + 0][lr] = wv.x; Ws[lc + 1][lr] = wv.y;
        Ws[lc + 2][lr] = wv.z; Ws[lc + 3][lr] = wv.w;
        __syncthreads();
#pragma unroll
        for (int k = 0; k < BK; k++) {
            float a[4], bv[4];
            *(float4*)a  = *(const float4*)&As[k][ty * 4];
            *(float4*)bv = *(const float4*)&Ws[k][tx * 4];
#pragma unroll
            for (int i = 0; i < 4; i++)
#pragma unroll
                for (int j = 0; j < 4; j++)
                    acc[i][j] = fmaf(a[i], bv[j], acc[i][j]);
        }
        __syncthreads();
    }

    int n = tx * 4;
    if (n < 48) {
        float* cp = Cpart + (size_t)blockIdx.y * M * 48;
#pragma unroll
        for (int i = 0; i < 4; i++) {
            float4 v = make_float4(acc[i][0], acc[i][1], acc[i][2], acc[i][3]);
            *(float4*)(cp + (size_t)(m0 + ty * 4 + i) * 48 + n) = v;
        }
    }
}

// deterministic 4-slice reduce: dbc = ((p0+p1)+(p2+p3)) -- same order the
// scans previously used in their staging sum (bit-identical).
__global__ __launch_bounds__(256) void k_dbr(
    const float* __restrict__ part, float* __restrict__ dbc, int M)
{
    int i = blockIdx.x * 256 + threadIdx.x;   // over M*48
    size_t st = (size_t)M * 48;
    dbc[i] = (part[i] + part[st + i]) + (part[2 * st + i] + part[3 * st + i]);
}

// ---------------------------------------------------------------------------
// depthwise causal conv1d (k=4) + SiLU, float4-vectorized, fused halo-save.
// ---------------------------------------------------------------------------
__global__ __launch_bounds__(256) void k_conv(
    const float* __restrict__ xz, float* __restrict__ halo,
    const float* __restrict__ cw, const float* __restrict__ cb,
    float* __restrict__ xc, int t0, int save_halo)
{
    size_t i4 = ((size_t)blockIdx.x * 256 + threadIdx.x) * 4;   // over RC*512
    int d  = (int)(i4 & 511);
    int r  = (int)(i4 >> 9);
    int b  = r & 31;
    int tl = r >> 5;

    float4 w0 = *(const float4*)(cw + (d + 0) * 4);
    float4 w1 = *(const float4*)(cw + (d + 1) * 4);
    float4 w2 = *(const float4*)(cw + (d + 2) * 4);
    float4 w3 = *(const float4*)(cw + (d + 3) * 4);
    float4 acc = *(const float4*)(cb + d);
    float4 vlast = make_float4(0.f, 0.f, 0.f, 0.f);

#pragma unroll
    for (int k = 0; k < 4; k++) {
        int tsl = tl - 3 + k;
        float4 v;
        if (tsl >= 0)
            v = *(const float4*)(xz + ((size_t)tsl * 32 + b) * 1024 + d);
        else if (t0 + tsl >= 0)
            v = *(const float4*)(halo + ((size_t)(tsl + 3) * 32 + b) * 512 + d);
        else
            continue;
        if (k == 3) vlast = v;
        acc.x = fmaf((&w0.x)[k], v.x, acc.x);
        acc.y = fmaf((&w1.x)[k], v.y, acc.y);
        acc.z = fmaf((&w2.x)[k], v.z, acc.z);
        acc.w = fmaf((&w3.x)[k], v.w, acc.w);
    }
    float4 o;
    o.x = acc.x / (1.f + __expf(-acc.x));
    o.y = acc.y / (1.f + __expf(-acc.y));
    o.z = acc.z / (1.f + __expf(-acc.z));
    o.w = acc.w / (1.f + __expf(-acc.w));
    *(float4*)(xc + i4) = o;

    if (save_halo && tl >= CH - 3)
        *(float4*)(halo + ((size_t)(tl - (CH - 3)) * 32 + b) * 512 + d) = vlast;
}

// ---------------------------------------------------------------------------
// scan pass A (fused dt-proj, geometric-dA, packed f32).
// B-row values are BLOCK-UNIFORM -> read straight from global dbc with
// blockIdx-derived (uniform) addresses: compiler emits s_load into SGPRs,
// removing all LDS staging + 24 ds_read_b64 per tt from the vector pipes.
// 512-thread blocks; SCT=32; next-tt xc prefetch. grid 32*NSC = 512.
// ---------------------------------------------------------------------------
__global__ __launch_bounds__(512) void k_scanA(
    const float* __restrict__ xc, const float* __restrict__ dbc,
    const float* __restrict__ dtw, const float* __restrict__ dtb,
    const float* __restrict__ A_log,
    float* __restrict__ hend, float* __restrict__ sumdt)
{
    int bx = blockIdx.x;
    int b = bx / NSC;
    int c = bx % NSC;
    int d = threadIdx.x;

    float A2[DS], wdt[DS];
#pragma unroll
    for (int s = 0; s < DS; s++) {
        A2[s] = -__expf(A_log[d * DS + s]) * LOG2E;
        wdt[s] = dtw[d * DS + s];
    }
    f32x2 h2[8];
#pragma unroll
    for (int j = 0; j < 8; j++) h2[j] = (f32x2){0.f, 0.f};
    f32x2 wdt2[8];
#pragma unroll
    for (int j = 0; j < 8; j++) { wdt2[j].x = wdt[2 * j]; wdt2[j].y = wdt[2 * j + 1]; }
    float dtbv = dtb[d];
    float A20 = A2[0];
    float A0nat = A20 * LN2;
    bool geo = true;
#pragma unroll
    for (int s = 0; s < DS; s++)
        geo = geo && (fabsf(A2[s] - (float)(s + 1) * A20) <=
                      1e-5f * fabsf(A2[s]) + 1e-30f);

    float cum = 0.f;
    if (geo) {
        const size_t idx0 = ((size_t)(c * SCT) * 32 + b) * DI + d;
        const size_t tstr = (size_t)32 * DI;
        float xv = xc[idx0];
        for (int tt = 0; tt < SCT; tt++) {
            float xcur = xv;
            if (tt + 1 < SCT) xv = xc[idx0 + (size_t)(tt + 1) * tstr];
            const float* br = dbc + ((size_t)(c * SCT + tt) * 32 + b) * 48;
            f32x2 pA, pB, pC, pD;
            pA.x = br[0] * wdt2[0].x; pA.y = br[1] * wdt2[0].y;
            pB.x = br[2] * wdt2[1].x; pB.y = br[3] * wdt2[1].y;
            pC.x = br[4] * wdt2[2].x; pC.y = br[5] * wdt2[2].y;
            pD.x = br[6] * wdt2[3].x; pD.y = br[7] * wdt2[3].y;
            pA.x = fmaf(br[8],  wdt2[4].x, pA.x); pA.y = fmaf(br[9],  wdt2[4].y, pA.y);
            pB.x = fmaf(br[10], wdt2[5].x, pB.x); pB.y = fmaf(br[11], wdt2[5].y, pB.y);
            pC.x = fmaf(br[12], wdt2[6].x, pC.x); pC.y = fmaf(br[13], wdt2[6].y, pC.y);
            pD.x = fmaf(br[14], wdt2[7].x, pD.x); pD.y = fmaf(br[15], wdt2[7].y, pD.y);
            f32x2 pE = (pA + pB) + (pC + pD);
            float s0 = dtbv + (pE.x + pE.y);
            float u  = __expf(s0);
            float t2 = __log2f(1.f + u);
            if (s0 > 80.f) t2 = s0 * LOG2E;
            float dt = LN2 * t2;
            cum += dt;
            float dtx = dt * xcur;
            float q  = exp2f(t2 * A0nat);
            float q2v = q * q;
            f32x2 qp; qp.x = q; qp.y = q2v;
            float rr = 1.f;
#pragma unroll
            for (int j = 0; j < 8; j++) {
                f32x2 dA2 = qp * rr;
                f32x2 bj; bj.x = br[16 + 2 * j]; bj.y = br[17 + 2 * j];
                h2[j] = dA2 * h2[j] + bj * dtx;
                rr *= q2v;
            }
        }
    } else {
        float h[DS];
#pragma unroll
        for (int s = 0; s < DS; s++) h[s] = 0.f;
        for (int tt = 0; tt < SCT; tt++) {
            size_t idx = ((size_t)(c * SCT + tt) * 32 + b) * DI + d;
            const float* br = dbc + ((size_t)(c * SCT + tt) * 32 + b) * 48;
            float s0 = dtbv;
#pragma unroll
            for (int k = 0; k < DS; k++) s0 = fmaf(br[k], wdt[k], s0);
            float dt = (s0 > 20.f) ? s0 : log1pf(expf(s0));
            cum += dt;
            float dtx = dt * xc[idx];
#pragma unroll
            for (int s = 0; s < DS; s++) {
                float dA = exp2f(dt * A2[s]);
                h[s] = fmaf(dA, h[s], dtx * br[16 + s]);
            }
        }
#pragma unroll
        for (int j = 0; j < 8; j++) { h2[j].x = h[2 * j]; h2[j].y = h[2 * j + 1]; }
    }
    f32x2* hp2 = (f32x2*)(hend + ((size_t)(c * 32 + b) * 512 + d) * DS);
#pragma unroll
    for (int j = 0; j < 8; j++) hp2[j] = h2[j];
    sumdt[((size_t)c * 32 + b) * 512 + d] = cum;
}

// ---------------------------------------------------------------------------
// scan pass B: carry across NSC=16 sub-chunks; hend -> h_init, carry -> hs.
// ---------------------------------------------------------------------------
__global__ __launch_bounds__(256) void k_scanB(
    const float* __restrict__ sumdt, float* __restrict__ hend,
    const float* __restrict__ A_log, float* __restrict__ hs, int first)
{
    int id = blockIdx.x * 256 + threadIdx.x;   // 32*512*16 = 262144
    int s = id & 15;
    int d = (id >> 4) & 511;
    int b = id >> 13;
    float A2 = -__expf(A_log[d * DS + s]) * LOG2E;
    size_t hsi = ((size_t)(b << 9) + d) * DS + s;
    float hin = first ? 0.f : hs[hsi];
    for (int c = 0; c < NSC; c++) {
        size_t hi = ((size_t)(c * 32 + b) * 512 + d) * DS + s;
        float he = hend[hi];
        float sd = sumdt[((size_t)c * 32 + b) * 512 + d];
        hend[hi] = hin;
        hin = fmaf(exp2f(A2 * sd), hin, he);
    }
    hs[hsi] = hin;
}

// ---------------------------------------------------------------------------
// scan pass C (fused dt-proj, geometric-dA, fast softplus, packed f32,
// uniform scalar dbc loads): 512-thread blocks; SCT=32; prefetch.
// ACC=0: emit y as bf16 hi/lo planes. ACC=1: accumulate t-sum into macc2.
// grid 32*NSC = 512 blocks.
// ---------------------------------------------------------------------------
template <int ACC>
__global__ __launch_bounds__(512) void k_scanC(
    const float* __restrict__ xc, const float* __restrict__ dbc,
    const float* __restrict__ dtw, const float* __restrict__ dtb,
    const float* __restrict__ xz,
    const float* __restrict__ A_log, const float* __restrict__ Dp,
    const float* __restrict__ hinit,
    u16* __restrict__ yh, u16* __restrict__ yl,
    float* __restrict__ macc2, int first)
{
    int bx = blockIdx.x;
    int b = bx / NSC;
    int c = bx % NSC;
    int d = threadIdx.x;

    float A2[DS], wdt[DS];
    const float* hp = hinit + ((size_t)(c * 32 + b) * 512 + d) * DS;
#pragma unroll
    for (int s = 0; s < DS; s++) {
        A2[s] = -__expf(A_log[d * DS + s]) * LOG2E;
        wdt[s] = dtw[d * DS + s];
    }
    f32x2 h2[8];
    {
        const f32x2* hp2 = (const f32x2*)hp;
#pragma unroll
        for (int j = 0; j < 8; j++) h2[j] = hp2[j];
    }
    f32x2 wdt2[8];
#pragma unroll
    for (int j = 0; j < 8; j++) { wdt2[j].x = wdt[2 * j]; wdt2[j].y = wdt[2 * j + 1]; }
    float dtbv = dtb[d];
    float Dv = Dp[d];
    float A20 = A2[0];
    float A0nat = A20 * LN2;
    bool geo = true;
#pragma unroll
    for (int s = 0; s < DS; s++)
        geo = geo && (fabsf(A2[s] - (float)(s + 1) * A20) <=
                      1e-5f * fabsf(A2[s]) + 1e-30f);

    float ysum = 0.f;
    if (geo) {
        const size_t row0 = (size_t)(c * SCT) * 32 + b;
        const size_t idx0 = row0 * DI + d;
        const size_t zi0  = (row0 << 10) + 512 + d;
        const size_t tstr = (size_t)32 * DI;
        const size_t zstr = (size_t)32 * 1024;
        float xv = xc[idx0];
        float zv = xz[zi0];
        for (int tt = 0; tt < SCT; tt++) {
            float xcur = xv, zcur = zv;
            if (tt + 1 < SCT) {
                xv = xc[idx0 + (size_t)(tt + 1) * tstr];
                zv = xz[zi0 + (size_t)(tt + 1) * zstr];
            }
            const float* br = dbc + ((size_t)(c * SCT + tt) * 32 + b) * 48;
            f32x2 pA, pB, pC, pD;
            pA.x = br[0] * wdt2[0].x; pA.y = br[1] * wdt2[0].y;
            pB.x = br[2] * wdt2[1].x; pB.y = br[3] * wdt2[1].y;
            pC.x = br[4] * wdt2[2].x; pC.y = br[5] * wdt2[2].y;
            pD.x = br[6] * wdt2[3].x; pD.y = br[7] * wdt2[3].y;
            pA.x = fmaf(br[8],  wdt2[4].x, pA.x); pA.y = fmaf(br[9],  wdt2[4].y, pA.y);
            pB.x = fmaf(br[10], wdt2[5].x, pB.x); pB.y = fmaf(br[11], wdt2[5].y, pB.y);
            pC.x = fmaf(br[12], wdt2[6].x, pC.x); pC.y = fmaf(br[13], wdt2[6].y, pC.y);
            pD.x = fmaf(br[14], wdt2[7].x, pD.x); pD.y = fmaf(br[15], wdt2[7].y, pD.y);
            f32x2 pE = (pA + pB) + (pC + pD);
            float s0 = dtbv + (pE.x + pE.y);
            float u  = __expf(s0);
            float t2 = __log2f(1.f + u);
            if (s0 > 80.f) t2 = s0 * LOG2E;
            float dt = LN2 * t2;
            float dtx = dt * xcur;
            float q  = exp2f(t2 * A0nat);
            float q2v = q * q;
            f32x2 qp; qp.x = q; qp.y = q2v;
            float rr = 1.f;
            f32x2 y2 = (f32x2){0.f, 0.f};
#pragma unroll
            for (int j = 0; j < 8; j++) {
                f32x2 dA2 = qp * rr;
                f32x2 bj; bj.x = br[16 + 2 * j]; bj.y = br[17 + 2 * j];
                f32x2 cj; cj.x = br[32 + 2 * j]; cj.y = br[33 + 2 * j];
                h2[j] = dA2 * h2[j] + bj * dtx;
                y2 = h2[j] * cj + y2;
                rr *= q2v;
            }
            float y = y2.x + y2.y;
            float yact = (y + xcur * Dv) * (zcur / (1.f + __expf(-zcur)));
            if (ACC) {
                ysum += yact;
            } else {
                size_t row = row0 + (size_t)tt * 32;
                unsigned hb = f2bf_u(yact);
                yh[row * DI + d] = (u16)hb;
                yl[row * DI + d] = (u16)f2bf_u(yact - __uint_as_float(hb << 16));
            }
        }
    } else {
        float h[DS];
#pragma unroll
        for (int j = 0; j < 8; j++) { h[2 * j] = h2[j].x; h[2 * j + 1] = h2[j].y; }
        for (int tt = 0; tt < SCT; tt++) {
            size_t row = (size_t)(c * SCT + tt) * 32 + b;
            size_t idx = row * DI + d;
            const float* br = dbc + ((size_t)(c * SCT + tt) * 32 + b) * 48;
            float s0 = dtbv;
#pragma unroll
            for (int k = 0; k < DS; k++) s0 = fmaf(br[k], wdt[k], s0);
            float dt = (s0 > 20.f) ? s0 : log1pf(expf(s0));
            float x  = xc[idx];
            float z  = xz[(row << 10) + 512 + d];
            float dtx = dt * x;
            float y = 0.f;
#pragma unroll
            for (int s = 0; s < DS; s++) {
                float dA = exp2f(dt * A2[s]);
                h[s] = fmaf(dA, h[s], dtx * br[16 + s]);
                y = fmaf(h[s], br[32 + s], y);
            }
            float yact = (y + x * Dv) * (z / (1.f + __expf(-z)));
            if (ACC) {
                ysum += yact;
            } else {
                unsigned hb = f2bf_u(yact);
                yh[row * DI + d] = (u16)hb;
                yl[row * DI + d] = (u16)f2bf_u(yact - __uint_as_float(hb << 16));
            }
        }
    }

    if (ACC) {
        size_t mi = ((size_t)(b * NSC + c) * 512) + d;
        if (first) macc2[mi] = ysum;
        else       macc2[mi] += ysum;
    }
}

// ---------------------------------------------------------------------------
// prehead: mm[b][n] = (1/1024) * sum_q Wo2[n][q] * (sum_c macc2[b][c][q])
// ---------------------------------------------------------------------------
__global__ __launch_bounds__(256) void k_prehead(
    const float* __restrict__ macc2, const float* __restrict__ wo2,
    float* __restrict__ mm)
{
    int b = blockIdx.x;
    int n = threadIdx.x;
    __shared__ float ys[512];
    for (int q = threadIdx.x; q < 512; q += 256) {
        float s = 0.f;
        for (int c = 0; c < NSC; c++)
            s += macc2[((size_t)(b * NSC + c) * 512) + q];
        ys[q] = s;
    }
    __syncthreads();
    const float* wr = wo2 + (size_t)n * 512;
    float s = 0.f;
    for (int q = 0; q < 512; q += 4) {
        float4 w = *(const float4*)(wr + q);
        s = fmaf(w.x, ys[q + 0], s);
        s = fmaf(w.y, ys[q + 1], s);
        s = fmaf(w.z, ys[q + 2], s);
        s = fmaf(w.w, ys[q + 3], s);
    }
    mm[b * 256 + n] = s * (1.f / 1024.f);
}

__global__ __launch_bounds__(128) void k_head(
    const float* __restrict__ mm, const float* __restrict__ xst,
    const float* __restrict__ h1w, const float* __restrict__ h1b,
    const float* __restrict__ h2w, const float* __restrict__ h2b,
    float* __restrict__ out)
{
    int b = blockIdx.x;
    int j = threadIdx.x;
    const float* wr = h1w + j * 261;
    const float* mr = mm + b * 256;
    float s = h1b[j];
    for (int k = 0; k < 256; k++) s = fmaf(mr[k], wr[k], s);
    for (int k = 0; k < 5; k++) s = fmaf(xst[b * 5 + k], wr[256 + k], s);
    float e = (s > 0.f) ? s : expm1f(s);

    __shared__ float sb[128];
    sb[j] = e * h2w[j];
    __syncthreads();
    for (int o = 64; o > 0; o >>= 1) {
        if (j < o) sb[j] += sb[j + o];
        __syncthreads();
    }
    if (j == 0) out[b] = sb[0] + h2b[0];
}

// ---------------------------------------------------------------------------
// host side
// ---------------------------------------------------------------------------
static void run_mamba_core(hipStream_t stream,
                           const u16* x1h, const u16* x1l, void* const* P,
                           const u16* wih, const u16* wil,
                           float* xzc, float* xcc, float* xpartb, float* dbcc,
                           u16* yh, u16* yl,
                           float* hendb, float* sumdtb, float* halo,
                           float* hstate, float* macc2, int acc,
                           int t0, int save_halo)
{
    const float* cw     = (const float*)P[1];
    const float* cb     = (const float*)P[2];
    const float* xpw    = (const float*)P[3];
    const float* dtw    = (const float*)P[4];
    const float* dtbias = (const float*)P[5];
    const float* Alog   = (const float*)P[6];
    const float* Dp     = (const float*)P[7];
    int first = (t0 == 0);

    k_gmfma<false><<<dim3(RC / 128, 1024 / 128), 256, 0, stream>>>(
        x1h, x1l, 256, wih, wil, nullptr, xzc, 1024, 256);
    k_conv<<<RC * DI / 1024, 256, 0, stream>>>(xzc, halo, cw, cb, xcc, t0, save_halo);
    k_xpart<<<dim3(RC / 64, 4), 256, 0, stream>>>(xcc, xpw, xpartb, RC, 512, 128);
    k_dbr<<<RC * 48 / 256, 256, 0, stream>>>(xpartb, dbcc, RC);
    k_scanA<<<32 * NSC, 512, 0, stream>>>(xcc, dbcc, dtw, dtbias, Alog,
                                          hendb, sumdtb);
    k_scanB<<<32 * 512 * DS / 256, 256, 0, stream>>>(sumdtb, hendb, Alog, hstate, first);
    if (acc)
        k_scanC<1><<<32 * NSC, 512, 0, stream>>>(
            xcc, dbcc, dtw, dtbias, xzc, Alog, Dp, hendb,
            nullptr, nullptr, macc2, first);
    else
        k_scanC<0><<<32 * NSC, 512, 0, stream>>>(
            xcc, dbcc, dtw, dtbias, xzc, Alog, Dp, hendb,
            yh, yl, nullptr, 0);
}

extern "C" void kernel_launch(void* const* d_in, const int* in_sizes, int n_in,
                              void* d_out, int out_size, void* d_ws, size_t ws_size,
                              hipStream_t stream)
{
    const float* xseq = (const float*)d_in[0];
    const float* xst  = (const float*)d_in[1];
    const float* p1w  = (const float*)d_in[2];
    const float* p1b  = (const float*)d_in[3];
    const float* ln1g = (const float*)d_in[4];
    const float* ln1b = (const float*)d_in[5];
    const float* p2w  = (const float*)d_in[6];
    const float* p2b  = (const float*)d_in[7];
    const float* ln2g = (const float*)d_in[8];
    const float* ln2b = (const float*)d_in[9];
    const float* h1w  = (const float*)d_in[10];
    const float* h1b  = (const float*)d_in[11];
    const float* h2w  = (const float*)d_in[12];
    const float* h2b  = (const float*)d_in[13];
    const float* wo1  = (const float*)d_in[22];   // m1 out_w [256,512]
    const float* wo2  = (const float*)d_in[31];   // m2 out_w [256,512]

    float* ws = (float*)d_ws;
    float* xzc    = ws;                                  // RC*1024 f32
    float* xcc    = xzc  + (size_t)RC * 1024;            // RC*512
    // hend region: NSC*32*512*DS = RC*256 floats; x1 planes alias its head
    float* hendb  = xcc  + (size_t)RC * 512;
    u16*   x1h    = (u16*)hendb;                         // RC*256 u16
    u16*   x1l    = x1h + (size_t)RC * 256;              // RC*256 u16
    float* hend_end = hendb + (size_t)NSC * 32 * 512 * DS;
    u16*   yh     = (u16*)hend_end;                      // RC*512 u16
    u16*   yl     = yh + (size_t)RC * 512;               // RC*512 u16
    float* sumdtb = (float*)(yl + (size_t)RC * 512);     // NSC*32*512
    float* halo1  = sumdtb + NSC * 32 * 512;             // 3*32*512
    float* halo2  = halo1 + 3 * 32 * 512;
    float* hs1    = halo2 + 3 * 32 * 512;                // 32*512*16
    float* hs2    = hs1  + 32 * 512 * DS;
    float* macc2  = hs2  + 32 * 512 * DS;                // 32*NSC*512 (1 MB)
    float* mm     = macc2 + 32 * NSC * 512;              // 32*256
    u16*   wm1ih  = (u16*)(mm + 32 * 256);               // 1024*256 u16 each
    u16*   wm1il  = wm1ih + 262144;
    u16*   wm2ih  = wm1il + 262144;
    u16*   wm2il  = wm2ih + 262144;
    u16*   wch    = wm2il + 262144;                      // 256*512 u16 each
    u16*   wcl    = wch + 131072;
    float* xpartb = (float*)(wcl + 131072);              // 4*RC*48 f32
    float* dbcc   = xpartb + 4 * (size_t)RC * 48;        // RC*48 f32
    size_t need = (size_t)((char*)(dbcc + (size_t)RC * 48) - (char*)ws);
    if (ws_size < need) return;   // tripwire: fail cleanly, don't fault

    // weight prep (2 launches total)
    k_wcvt2<<<2048, 256, 0, stream>>>(
        (const float*)d_in[14], (const float*)d_in[23],
        wm1ih, wm1il, wm2ih, wm2il);
    k_wcomb<<<512, 256, 0, stream>>>(p2w, wo1, wch, wcl);

    for (int c = 0; c < NCH; c++) {
        int t0 = c * CH;
        int save_halo = (c != NCH - 1);

        k_p1_ln<<<RC, 256, 0, stream>>>(xseq, p1w, p1b, ln1g, ln1b, x1h, x1l, t0);

        // mamba 1 core (params d_in[14..22]) -> y planes
        run_mamba_core(stream, x1h, x1l, d_in + 14, wm1ih, wm1il,
                       xzc, xcc, xpartb, dbcc, yh, yl,
                       hendb, sumdtb, halo1, hs1, nullptr, 0, t0, save_halo);

        // fused out_proj1+p2 (y @ Wc^T + p2b) -> LN2
        k_gmfma<true><<<dim3(RC / 128, 256 / 128), 256, 0, stream>>>(
            yh, yl, 512, wch, wcl, p2b, xzc, 256, 512);
        k_ln<<<RC, 256, 0, stream>>>(xzc, ln2g, ln2b, x1h, x1l);

        // mamba 2 core (params d_in[23..31]); y accumulated into macc2,
        // out_proj folded into prehead
        run_mamba_core(stream, x1h, x1l, d_in + 23, wm2ih, wm2il,
                       xzc, xcc, xpartb, dbcc, yh, yl,
                       hendb, sumdtb, halo2, hs2, macc2, 1, t0, save_halo);
    }

    k_prehead<<<NB, 256, 0, stream>>>(macc2, wo2, mm);
    k_head<<<NB, 128, 0, stream>>>(mm, xst, h1w, h1b, h2w, h2b, (float*)d_out);
}

// Round 23
// 698.830 us; speedup vs baseline: 1.0219x; 1.0219x over previous
//
#include <hip/hip_runtime.h>
#include <math.h>

#define NB 32
#define L  1024
#define CH 512                 // timesteps per chunk
#define NCH (L / CH)           // 2 chunks
#define RC (NB * CH)           // 16384 rows per chunk
#define DM 256
#define DI 512
#define DS 16
#define SCT 32                 // sub-chunk timesteps (scan)
#define NSC (CH / SCT)         // 16 sub-chunks
#define LOG2E 1.44269504f
#define LN2   0.69314718f

typedef short short8 __attribute__((ext_vector_type(8)));
typedef float f32x4 __attribute__((ext_vector_type(4)));
typedef float f32x2 __attribute__((ext_vector_type(2)));
typedef unsigned short u16;

// bf16 split helpers: x ~= hi + lo, both bf16 (rne).
__device__ inline unsigned f2bf_u(float x) {
    unsigned u = __float_as_uint(x);
    return (u + 0x7fffu + ((u >> 16) & 1u)) >> 16;
}

// Layout: per-chunk activations use (t_local, b, feat): row r = t_local*32 + b.

// ---------------------------------------------------------------------------
// p1 (K=4) + bias + LayerNorm; emits bf16 hi/lo PLANES for MFMA in_proj.
// ---------------------------------------------------------------------------
__global__ __launch_bounds__(256) void k_p1_ln(
    const float* __restrict__ xseq, const float* __restrict__ w,
    const float* __restrict__ bias, const float* __restrict__ g,
    const float* __restrict__ bb, u16* __restrict__ outh, u16* __restrict__ outl,
    int t0)
{
    int r  = blockIdx.x;
    int b  = r & 31;
    int tl = r >> 5;
    int m  = threadIdx.x;
    const float* xr = xseq + ((size_t)b * L + t0 + tl) * 4;
    float x0 = xr[0], x1 = xr[1], x2 = xr[2], x3 = xr[3];
    const float* wr = w + m * 4;
    float v = bias[m] + x0 * wr[0] + x1 * wr[1] + x2 * wr[2] + x3 * wr[3];

    __shared__ float s1[4], s2[4];
    float a = v, bq = v * v;
    for (int o = 32; o > 0; o >>= 1) { a += __shfl_down(a, o); bq += __shfl_down(bq, o); }
    int wid = m >> 6, lane = m & 63;
    if (lane == 0) { s1[wid] = a; s2[wid] = bq; }
    __syncthreads();
    if (m == 0) {
        s1[0] = s1[0] + s1[1] + s1[2] + s1[3];
        s2[0] = s2[0] + s2[1] + s2[2] + s2[3];
    }
    __syncthreads();
    float mu  = s1[0] * (1.f / 256.f);
    float var = s2[0] * (1.f / 256.f) - mu * mu;
    float o2 = (v - mu) * rsqrtf(var + 1e-5f) * g[m] + bb[m];
    unsigned hb = f2bf_u(o2);
    outh[(size_t)r * 256 + m] = (u16)hb;
    outl[(size_t)r * 256 + m] = (u16)f2bf_u(o2 - __uint_as_float(hb << 16));
}

// ---------------------------------------------------------------------------
// LayerNorm over 256; fp32 in, bf16 hi/lo planes out.
// ---------------------------------------------------------------------------
__global__ __launch_bounds__(256) void k_ln(
    const float* __restrict__ in, const float* __restrict__ g,
    const float* __restrict__ bb, u16* __restrict__ outh, u16* __restrict__ outl)
{
    int r = blockIdx.x;
    int m = threadIdx.x;
    float v = in[(size_t)r * 256 + m];

    __shared__ float s1[4], s2[4];
    float a = v, bq = v * v;
    for (int o = 32; o > 0; o >>= 1) { a += __shfl_down(a, o); bq += __shfl_down(bq, o); }
    int wid = m >> 6, lane = m & 63;
    if (lane == 0) { s1[wid] = a; s2[wid] = bq; }
    __syncthreads();
    if (m == 0) {
        s1[0] = s1[0] + s1[1] + s1[2] + s1[3];
        s2[0] = s2[0] + s2[1] + s2[2] + s2[3];
    }
    __syncthreads();
    float mu  = s1[0] * (1.f / 256.f);
    float var = s2[0] * (1.f / 256.f) - mu * mu;
    float o2 = (v - mu) * rsqrtf(var + 1e-5f) * g[m] + bb[m];
    unsigned hb = f2bf_u(o2);
    outh[(size_t)r * 256 + m] = (u16)hb;
    outl[(size_t)r * 256 + m] = (u16)f2bf_u(o2 - __uint_as_float(hb << 16));
}

// ---------------------------------------------------------------------------
// in_proj weight conversion (2 matrices) -> hi/lo planes, 1 launch.
// ---------------------------------------------------------------------------
__global__ __launch_bounds__(256) void k_wcvt2(
    const float* __restrict__ w1i, const float* __restrict__ w2i,
    u16* __restrict__ o1h, u16* __restrict__ o1l,
    u16* __restrict__ o2h, u16* __restrict__ o2l)
{
    int i = blockIdx.x * 256 + threadIdx.x;     // 524288, grid 2048
    const float* src; u16 *oh, *ol; int j;
    if (i < 262144) { src = w1i; oh = o1h; ol = o1l; j = i; }
    else            { src = w2i; oh = o2h; ol = o2l; j = i - 262144; }
    float v = src[j];
    unsigned hb = f2bf_u(v);
    oh[j] = (u16)hb;
    ol[j] = (u16)f2bf_u(v - __uint_as_float(hb << 16));
}

// ---------------------------------------------------------------------------
// combined weight Wc = Wp2 @ Wo1  ([256,256]x[256,512] -> [256,512]),
// packed to hi/lo planes.  (y@Wo1^T)@Wp2^T + b == y@Wc^T + b  (exact algebra)
// ---------------------------------------------------------------------------
__global__ __launch_bounds__(256) void k_wcomb(
    const float* __restrict__ p2w, const float* __restrict__ outw,
    u16* __restrict__ och, u16* __restrict__ ocl)
{
    int idx = blockIdx.x * 256 + threadIdx.x;   // 131072, grid 512
    int n = idx >> 9, k = idx & 511;
    const float* pr = p2w + n * 256;
    float s = 0.f;
    for (int j = 0; j < 256; j++)
        s = fmaf(pr[j], outw[(size_t)j * 512 + k], s);
    unsigned hb = f2bf_u(s);
    och[idx] = (u16)hb;
    ocl[idx] = (u16)f2bf_u(s - __uint_as_float(hb << 16));
}

// ---------------------------------------------------------------------------
// split-bf16 MFMA GEMM (3-term): C[M,N] = A[M,K]*W[N,K]^T (+bias).
// A,W as separate hi/lo bf16 planes. 128x128 tile, BK=32. fp32 output.
// ---------------------------------------------------------------------------
template <bool BIAS>
__global__ __launch_bounds__(256) void k_gmfma(
    const u16* __restrict__ Ahg, const u16* __restrict__ Alg, int lda,
    const u16* __restrict__ Whg, const u16* __restrict__ Wlg,
    const float* __restrict__ bias, float* __restrict__ C0,
    int N, int K)
{
    __shared__ u16 Ah[128 * 40], Al[128 * 40];
    __shared__ u16 Wh[128 * 40], Wl[128 * 40];

    int tid = threadIdx.x;
    int wv = tid >> 6, ln = tid & 63;
    int wr = wv >> 1, wc = wv & 1;
    int m0 = blockIdx.x * 128, n0 = blockIdx.y * 128;
    int sr = tid >> 1, sk = (tid & 1) << 4;
    int frow = ln & 15, fk = (ln >> 4) << 3;

    f32x4 acc[4][4] = {};

    for (int k0 = 0; k0 < K; k0 += 32) {
        const u16* ah = Ahg + (size_t)(m0 + sr) * lda + k0 + sk;
        const u16* al = Alg + (size_t)(m0 + sr) * lda + k0 + sk;
        const u16* wh = Whg + (size_t)(n0 + sr) * K + k0 + sk;
        const u16* wl = Wlg + (size_t)(n0 + sr) * K + k0 + sk;
        short8 vah0 = *(const short8*)ah, vah1 = *(const short8*)(ah + 8);
        short8 val0 = *(const short8*)al, val1 = *(const short8*)(al + 8);
        short8 vwh0 = *(const short8*)wh, vwh1 = *(const short8*)(wh + 8);
        short8 vwl0 = *(const short8*)wl, vwl1 = *(const short8*)(wl + 8);

        __syncthreads();   // previous iteration's frag reads done

        *(short8*)&Ah[sr * 40 + sk]     = vah0;
        *(short8*)&Ah[sr * 40 + sk + 8] = vah1;
        *(short8*)&Al[sr * 40 + sk]     = val0;
        *(short8*)&Al[sr * 40 + sk + 8] = val1;
        *(short8*)&Wh[sr * 40 + sk]     = vwh0;
        *(short8*)&Wh[sr * 40 + sk + 8] = vwh1;
        *(short8*)&Wl[sr * 40 + sk]     = vwl0;
        *(short8*)&Wl[sr * 40 + sk + 8] = vwl1;

        __syncthreads();

        short8 afh[4], afl[4], wfh[4], wfl[4];
#pragma unroll
        for (int g = 0; g < 4; g++) {
            int ra = (wr * 64 + g * 16 + frow) * 40 + fk;
            int rw = (wc * 64 + g * 16 + frow) * 40 + fk;
            afh[g] = *(const short8*)&Ah[ra];
            afl[g] = *(const short8*)&Al[ra];
            wfh[g] = *(const short8*)&Wh[rw];
            wfl[g] = *(const short8*)&Wl[rw];
        }
#pragma unroll
        for (int mg = 0; mg < 4; mg++)
#pragma unroll
            for (int ng = 0; ng < 4; ng++) {
                acc[mg][ng] = __builtin_amdgcn_mfma_f32_16x16x32_bf16(afh[mg], wfh[ng], acc[mg][ng], 0, 0, 0);
                acc[mg][ng] = __builtin_amdgcn_mfma_f32_16x16x32_bf16(afh[mg], wfl[ng], acc[mg][ng], 0, 0, 0);
                acc[mg][ng] = __builtin_amdgcn_mfma_f32_16x16x32_bf16(afl[mg], wfh[ng], acc[mg][ng], 0, 0, 0);
            }
    }

    // C layout: col=lane&15, row=(lane>>4)*4+reg  [verified m89]
#pragma unroll
    for (int ng = 0; ng < 4; ng++) {
        int col = n0 + wc * 64 + ng * 16 + frow;
        float bv = BIAS ? bias[col] : 0.f;
#pragma unroll
        for (int mg = 0; mg < 4; mg++)
#pragma unroll
            for (int r = 0; r < 4; r++) {
                int row = m0 + wr * 64 + mg * 16 + (ln >> 4) * 4 + r;
                C0[(size_t)row * N + col] = acc[mg][ng][r] + bv;
            }
    }
}

// ---------------------------------------------------------------------------
// xproj K-split partial GEMM: Cpart[slice][M][48] = A[:, ks..ks+128) * W^T.
// grid (M/64, 4). Partials summed inside the scans (exact dbr order).
// ---------------------------------------------------------------------------
__global__ __launch_bounds__(256) void k_xpart(
    const float* __restrict__ A, const float* __restrict__ W,
    float* __restrict__ Cpart, int M, int K, int kcnt)
{
    const int BM = 64, BK = 16;
    __shared__ float As[BK][BM];
    __shared__ float Ws[BK][64];

    int m0   = blockIdx.x * BM;
    int kbeg = blockIdx.y * kcnt;
    int tid = threadIdx.x;
    int tx  = tid & 15, ty = tid >> 4;
    int lr  = tid >> 2;
    int lc  = (tid & 3) * 4;

    float acc[4][4] = {};

    for (int k0 = kbeg; k0 < kbeg + kcnt; k0 += BK) {
        float4 av = *(const float4*)(A + (size_t)(m0 + lr) * K + k0 + lc);
        As[lc + 0][lr] = av.x; As[lc + 1][lr] = av.y;
        As[lc + 2][lr] = av.z; As[lc + 3][lr] = av.w;
        float4 wv = make_float4(0.f, 0.f, 0.f, 0.f);
        if (lr < 48) wv = *(const float4*)(W + (size_t)lr * K + k0 + lc);
        Ws[lc + 0][lr] = wv.x; Ws[lc + 1][lr] = wv.y;
        Ws[lc + 2][lr] = wv.z; Ws[lc + 3][lr] = wv.w;
        __syncthreads();
#pragma unroll
        for (int k = 0; k < BK; k++) {
            float a[4], bv[4];
            *(float4*)a  = *(const float4*)&As[k][ty * 4];
            *(float4*)bv = *(const float4*)&Ws[k][tx * 4];
#pragma unroll
            for (int i = 0; i < 4; i++)
#pragma unroll
                for (int j = 0; j < 4; j++)
                    acc[i][j] = fmaf(a[i], bv[j], acc[i][j]);
        }
        __syncthreads();
    }

    int n = tx * 4;
    if (n < 48) {
        float* cp = Cpart + (size_t)blockIdx.y * M * 48;
#pragma unroll
        for (int i = 0; i < 4; i++) {
            float4 v = make_float4(acc[i][0], acc[i][1], acc[i][2], acc[i][3]);
            *(float4*)(cp + (size_t)(m0 + ty * 4 + i) * 48 + n) = v;
        }
    }
}

// ---------------------------------------------------------------------------
// depthwise causal conv1d (k=4) + SiLU, float4-vectorized, fused halo-save.
// ---------------------------------------------------------------------------
__global__ __launch_bounds__(256) void k_conv(
    const float* __restrict__ xz, float* __restrict__ halo,
    const float* __restrict__ cw, const float* __restrict__ cb,
    float* __restrict__ xc, int t0, int save_halo)
{
    size_t i4 = ((size_t)blockIdx.x * 256 + threadIdx.x) * 4;   // over RC*512
    int d  = (int)(i4 & 511);
    int r  = (int)(i4 >> 9);
    int b  = r & 31;
    int tl = r >> 5;

    float4 w0 = *(const float4*)(cw + (d + 0) * 4);
    float4 w1 = *(const float4*)(cw + (d + 1) * 4);
    float4 w2 = *(const float4*)(cw + (d + 2) * 4);
    float4 w3 = *(const float4*)(cw + (d + 3) * 4);
    float4 acc = *(const float4*)(cb + d);
    float4 vlast = make_float4(0.f, 0.f, 0.f, 0.f);

#pragma unroll
    for (int k = 0; k < 4; k++) {
        int tsl = tl - 3 + k;
        float4 v;
        if (tsl >= 0)
            v = *(const float4*)(xz + ((size_t)tsl * 32 + b) * 1024 + d);
        else if (t0 + tsl >= 0)
            v = *(const float4*)(halo + ((size_t)(tsl + 3) * 32 + b) * 512 + d);
        else
            continue;
        if (k == 3) vlast = v;
        acc.x = fmaf((&w0.x)[k], v.x, acc.x);
        acc.y = fmaf((&w1.x)[k], v.y, acc.y);
        acc.z = fmaf((&w2.x)[k], v.z, acc.z);
        acc.w = fmaf((&w3.x)[k], v.w, acc.w);
    }
    float4 o;
    o.x = acc.x / (1.f + __expf(-acc.x));
    o.y = acc.y / (1.f + __expf(-acc.y));
    o.z = acc.z / (1.f + __expf(-acc.z));
    o.w = acc.w / (1.f + __expf(-acc.w));
    *(float4*)(xc + i4) = o;

    if (save_halo && tl >= CH - 3)
        *(float4*)(halo + ((size_t)(tl - (CH - 3)) * 32 + b) * 512 + d) = vlast;
}

// ---------------------------------------------------------------------------
// scan pass A (fused dt-proj + partial-reduce, geometric-dA, packed f32
// pairs for the h-update -> v_pk_fma_f32). 512-thread blocks; SCT=32;
// next-tt xc prefetch. grid 32*NSC = 512 blocks.
// ---------------------------------------------------------------------------
__global__ __launch_bounds__(512) void k_scanA(
    const float* __restrict__ xc, const float* __restrict__ part,
    const float* __restrict__ dtw, const float* __restrict__ dtb,
    const float* __restrict__ A_log,
    float* __restrict__ hend, float* __restrict__ sumdt)
{
    int bx = blockIdx.x;
    int b = bx / NSC;
    int c = bx % NSC;
    int d = threadIdx.x;

    float A2[DS], wdt[DS];
#pragma unroll
    for (int s = 0; s < DS; s++) {
        A2[s] = -__expf(A_log[d * DS + s]) * LOG2E;
        wdt[s] = dtw[d * DS + s];
    }
    f32x2 h2[8];
#pragma unroll
    for (int j = 0; j < 8; j++) h2[j] = (f32x2){0.f, 0.f};
    f32x2 wdt2[8];
#pragma unroll
    for (int j = 0; j < 8; j++) { wdt2[j].x = wdt[2 * j]; wdt2[j].y = wdt[2 * j + 1]; }
    float dtbv = dtb[d];
    float A20 = A2[0];
    float A0nat = A20 * LN2;
    bool geo = true;
#pragma unroll
    for (int s = 0; s < DS; s++)
        geo = geo && (fabsf(A2[s] - (float)(s + 1) * A20) <=
                      1e-5f * fabsf(A2[s]) + 1e-30f);

    __shared__ float Bs[SCT][48];
    {
        const size_t st = (size_t)RC * 48;
        for (int f = threadIdx.x; f < SCT * 48; f += 512) {
            int tt = f / 48, jj = f - tt * 48;
            size_t base = ((size_t)(c * SCT + tt) * 32 + b) * 48 + jj;
            Bs[tt][jj] = (part[base] + part[st + base]) +
                         (part[2 * st + base] + part[3 * st + base]);
        }
    }
    __syncthreads();

    float cum = 0.f;
    if (geo) {
        const size_t idx0 = ((size_t)(c * SCT) * 32 + b) * DI + d;
        const size_t tstr = (size_t)32 * DI;
        float xv = xc[idx0];
        for (int tt = 0; tt < SCT; tt++) {
            float xcur = xv;
            if (tt + 1 < SCT) xv = xc[idx0 + (size_t)(tt + 1) * tstr];
            const f32x2* bs2 = (const f32x2*)&Bs[tt][0];
            f32x2 pA = bs2[0] * wdt2[0];
            f32x2 pB = bs2[1] * wdt2[1];
            f32x2 pC = bs2[2] * wdt2[2];
            f32x2 pD = bs2[3] * wdt2[3];
            pA = bs2[4] * wdt2[4] + pA;
            pB = bs2[5] * wdt2[5] + pB;
            pC = bs2[6] * wdt2[6] + pC;
            pD = bs2[7] * wdt2[7] + pD;
            f32x2 pE = (pA + pB) + (pC + pD);
            float s0 = dtbv + (pE.x + pE.y);
            float u  = __expf(s0);
            float t2 = __log2f(1.f + u);
            if (s0 > 80.f) t2 = s0 * LOG2E;
            float dt = LN2 * t2;
            cum += dt;
            float dtx = dt * xcur;
            float q  = exp2f(t2 * A0nat);
            float q2v = q * q;
            f32x2 qp; qp.x = q; qp.y = q2v;
            float rr = 1.f;
#pragma unroll
            for (int j = 0; j < 8; j++) {
                f32x2 dA2 = qp * rr;
                h2[j] = dA2 * h2[j] + bs2[8 + j] * dtx;
                rr *= q2v;
            }
        }
    } else {
        float h[DS];
#pragma unroll
        for (int s = 0; s < DS; s++) h[s] = 0.f;
        for (int tt = 0; tt < SCT; tt++) {
            size_t idx = ((size_t)(c * SCT + tt) * 32 + b) * DI + d;
            float s0 = dtbv;
#pragma unroll
            for (int k = 0; k < DS; k++) s0 = fmaf(Bs[tt][k], wdt[k], s0);
            float dt = (s0 > 20.f) ? s0 : log1pf(expf(s0));
            cum += dt;
            float dtx = dt * xc[idx];
#pragma unroll
            for (int s = 0; s < DS; s++) {
                float dA = exp2f(dt * A2[s]);
                h[s] = fmaf(dA, h[s], dtx * Bs[tt][16 + s]);
            }
        }
#pragma unroll
        for (int j = 0; j < 8; j++) { h2[j].x = h[2 * j]; h2[j].y = h[2 * j + 1]; }
    }
    f32x2* hp2 = (f32x2*)(hend + ((size_t)(c * 32 + b) * 512 + d) * DS);
#pragma unroll
    for (int j = 0; j < 8; j++) hp2[j] = h2[j];
    sumdt[((size_t)c * 32 + b) * 512 + d] = cum;
}

// ---------------------------------------------------------------------------
// scan pass B: carry across NSC=16 sub-chunks; hend -> h_init, carry -> hs.
// ---------------------------------------------------------------------------
__global__ __launch_bounds__(256) void k_scanB(
    const float* __restrict__ sumdt, float* __restrict__ hend,
    const float* __restrict__ A_log, float* __restrict__ hs, int first)
{
    int id = blockIdx.x * 256 + threadIdx.x;   // 32*512*16 = 262144
    int s = id & 15;
    int d = (id >> 4) & 511;
    int b = id >> 13;
    float A2 = -__expf(A_log[d * DS + s]) * LOG2E;
    size_t hsi = ((size_t)(b << 9) + d) * DS + s;
    float hin = first ? 0.f : hs[hsi];
    for (int c = 0; c < NSC; c++) {
        size_t hi = ((size_t)(c * 32 + b) * 512 + d) * DS + s;
        float he = hend[hi];
        float sd = sumdt[((size_t)c * 32 + b) * 512 + d];
        hend[hi] = hin;
        hin = fmaf(exp2f(A2 * sd), hin, he);
    }
    hs[hsi] = hin;
}

// ---------------------------------------------------------------------------
// scan pass C (fused dt-proj + partial-reduce, geometric-dA, fast softplus,
// packed f32 pairs -> v_pk_fma_f32): 512-thread blocks; SCT=32; prefetch.
// ACC=0: emit y as bf16 hi/lo planes. ACC=1: accumulate t-sum into macc2.
// grid 32*NSC = 512 blocks.
// ---------------------------------------------------------------------------
template <int ACC>
__global__ __launch_bounds__(512) void k_scanC(
    const float* __restrict__ xc, const float* __restrict__ part,
    const float* __restrict__ dtw, const float* __restrict__ dtb,
    const float* __restrict__ xz,
    const float* __restrict__ A_log, const float* __restrict__ Dp,
    const float* __restrict__ hinit,
    u16* __restrict__ yh, u16* __restrict__ yl,
    float* __restrict__ macc2, int first)
{
    int bx = blockIdx.x;
    int b = bx / NSC;
    int c = bx % NSC;
    int d = threadIdx.x;

    float A2[DS], wdt[DS];
    const float* hp = hinit + ((size_t)(c * 32 + b) * 512 + d) * DS;
#pragma unroll
    for (int s = 0; s < DS; s++) {
        A2[s] = -__expf(A_log[d * DS + s]) * LOG2E;
        wdt[s] = dtw[d * DS + s];
    }
    f32x2 h2[8];
    {
        const f32x2* hp2 = (const f32x2*)hp;
#pragma unroll
        for (int j = 0; j < 8; j++) h2[j] = hp2[j];
    }
    f32x2 wdt2[8];
#pragma unroll
    for (int j = 0; j < 8; j++) { wdt2[j].x = wdt[2 * j]; wdt2[j].y = wdt[2 * j + 1]; }
    float dtbv = dtb[d];
    float Dv = Dp[d];
    float A20 = A2[0];
    float A0nat = A20 * LN2;
    bool geo = true;
#pragma unroll
    for (int s = 0; s < DS; s++)
        geo = geo && (fabsf(A2[s] - (float)(s + 1) * A20) <=
                      1e-5f * fabsf(A2[s]) + 1e-30f);

    __shared__ float BC[SCT][48];
    {
        const size_t st = (size_t)RC * 48;
        for (int f = threadIdx.x; f < SCT * 48; f += 512) {
            int tt = f / 48, jj = f - tt * 48;
            size_t base = ((size_t)(c * SCT + tt) * 32 + b) * 48 + jj;
            BC[tt][jj] = (part[base] + part[st + base]) +
                         (part[2 * st + base] + part[3 * st + base]);
        }
    }
    __syncthreads();

    float ysum = 0.f;
    if (geo) {
        const size_t row0 = (size_t)(c * SCT) * 32 + b;
        const size_t idx0 = row0 * DI + d;
        const size_t zi0  = (row0 << 10) + 512 + d;
        const size_t tstr = (size_t)32 * DI;
        const size_t zstr = (size_t)32 * 1024;
        float xv = xc[idx0];
        float zv = xz[zi0];
        for (int tt = 0; tt < SCT; tt++) {
            float xcur = xv, zcur = zv;
            if (tt + 1 < SCT) {
                xv = xc[idx0 + (size_t)(tt + 1) * tstr];
                zv = xz[zi0 + (size_t)(tt + 1) * zstr];
            }
            const f32x2* bc2 = (const f32x2*)&BC[tt][0];
            f32x2 pA = bc2[0] * wdt2[0];
            f32x2 pB = bc2[1] * wdt2[1];
            f32x2 pC = bc2[2] * wdt2[2];
            f32x2 pD = bc2[3] * wdt2[3];
            pA = bc2[4] * wdt2[4] + pA;
            pB = bc2[5] * wdt2[5] + pB;
            pC = bc2[6] * wdt2[6] + pC;
            pD = bc2[7] * wdt2[7] + pD;
            f32x2 pE = (pA + pB) + (pC + pD);
            float s0 = dtbv + (pE.x + pE.y);
            float u  = __expf(s0);
            float t2 = __log2f(1.f + u);
            if (s0 > 80.f) t2 = s0 * LOG2E;
            float dt = LN2 * t2;
            float dtx = dt * xcur;
            float q  = exp2f(t2 * A0nat);
            float q2v = q * q;
            f32x2 qp; qp.x = q; qp.y = q2v;
            float rr = 1.f;
            f32x2 y2 = (f32x2){0.f, 0.f};
#pragma unroll
            for (int j = 0; j < 8; j++) {
                f32x2 dA2 = qp * rr;
                h2[j] = dA2 * h2[j] + bc2[8 + j] * dtx;
                y2 = h2[j] * bc2[16 + j] + y2;
                rr *= q2v;
            }
            float y = y2.x + y2.y;
            float yact = (y + xcur * Dv) * (zcur / (1.f + __expf(-zcur)));
            if (ACC) {
                ysum += yact;
            } else {
                size_t row = row0 + (size_t)tt * 32;
                unsigned hb = f2bf_u(yact);
                yh[row * DI + d] = (u16)hb;
                yl[row * DI + d] = (u16)f2bf_u(yact - __uint_as_float(hb << 16));
            }
        }
    } else {
        float h[DS];
#pragma unroll
        for (int j = 0; j < 8; j++) { h[2 * j] = h2[j].x; h[2 * j + 1] = h2[j].y; }
        for (int tt = 0; tt < SCT; tt++) {
            size_t row = (size_t)(c * SCT + tt) * 32 + b;
            size_t idx = row * DI + d;
            float s0 = dtbv;
#pragma unroll
            for (int k = 0; k < DS; k++) s0 = fmaf(BC[tt][k], wdt[k], s0);
            float dt = (s0 > 20.f) ? s0 : log1pf(expf(s0));
            float x  = xc[idx];
            float z  = xz[(row << 10) + 512 + d];
            float dtx = dt * x;
            float y = 0.f;
#pragma unroll
            for (int s = 0; s < DS; s++) {
                float dA = exp2f(dt * A2[s]);
                h[s] = fmaf(dA, h[s], dtx * BC[tt][16 + s]);
                y = fmaf(h[s], BC[tt][32 + s], y);
            }
            float yact = (y + x * Dv) * (z / (1.f + __expf(-z)));
            if (ACC) {
                ysum += yact;
            } else {
                unsigned hb = f2bf_u(yact);
                yh[row * DI + d] = (u16)hb;
                yl[row * DI + d] = (u16)f2bf_u(yact - __uint_as_float(hb << 16));
            }
        }
    }

    if (ACC) {
        size_t mi = ((size_t)(b * NSC + c) * 512) + d;
        if (first) macc2[mi] = ysum;
        else       macc2[mi] += ysum;
    }
}

// ---------------------------------------------------------------------------
// prehead: mm[b][n] = (1/1024) * sum_q Wo2[n][q] * (sum_c macc2[b][c][q])
// ---------------------------------------------------------------------------
__global__ __launch_bounds__(256) void k_prehead(
    const float* __restrict__ macc2, const float* __restrict__ wo2,
    float* __restrict__ mm)
{
    int b = blockIdx.x;
    int n = threadIdx.x;
    __shared__ float ys[512];
    for (int q = threadIdx.x; q < 512; q += 256) {
        float s = 0.f;
        for (int c = 0; c < NSC; c++)
            s += macc2[((size_t)(b * NSC + c) * 512) + q];
        ys[q] = s;
    }
    __syncthreads();
    const float* wr = wo2 + (size_t)n * 512;
    float s = 0.f;
    for (int q = 0; q < 512; q += 4) {
        float4 w = *(const float4*)(wr + q);
        s = fmaf(w.x, ys[q + 0], s);
        s = fmaf(w.y, ys[q + 1], s);
        s = fmaf(w.z, ys[q + 2], s);
        s = fmaf(w.w, ys[q + 3], s);
    }
    mm[b * 256 + n] = s * (1.f / 1024.f);
}

__global__ __launch_bounds__(128) void k_head(
    const float* __restrict__ mm, const float* __restrict__ xst,
    const float* __restrict__ h1w, const float* __restrict__ h1b,
    const float* __restrict__ h2w, const float* __restrict__ h2b,
    float* __restrict__ out)
{
    int b = blockIdx.x;
    int j = threadIdx.x;
    const float* wr = h1w + j * 261;
    const float* mr = mm + b * 256;
    float s = h1b[j];
    for (int k = 0; k < 256; k++) s = fmaf(mr[k], wr[k], s);
    for (int k = 0; k < 5; k++) s = fmaf(xst[b * 5 + k], wr[256 + k], s);
    float e = (s > 0.f) ? s : expm1f(s);

    __shared__ float sb[128];
    sb[j] = e * h2w[j];
    __syncthreads();
    for (int o = 64; o > 0; o >>= 1) {
        if (j < o) sb[j] += sb[j + o];
        __syncthreads();
    }
    if (j == 0) out[b] = sb[0] + h2b[0];
}

// ---------------------------------------------------------------------------
// host side
// ---------------------------------------------------------------------------
static void run_mamba_core(hipStream_t stream,
                           const u16* x1h, const u16* x1l, void* const* P,
                           const u16* wih, const u16* wil,
                           float* xzc, float* xcc, float* xpartb,
                           u16* yh, u16* yl,
                           float* hendb, float* sumdtb, float* halo,
                           float* hstate, float* macc2, int acc,
                           int t0, int save_halo)
{
    const float* cw     = (const float*)P[1];
    const float* cb     = (const float*)P[2];
    const float* xpw    = (const float*)P[3];
    const float* dtw    = (const float*)P[4];
    const float* dtbias = (const float*)P[5];
    const float* Alog   = (const float*)P[6];
    const float* Dp     = (const float*)P[7];
    int first = (t0 == 0);

    k_gmfma<false><<<dim3(RC / 128, 1024 / 128), 256, 0, stream>>>(
        x1h, x1l, 256, wih, wil, nullptr, xzc, 1024, 256);
    k_conv<<<RC * DI / 1024, 256, 0, stream>>>(xzc, halo, cw, cb, xcc, t0, save_halo);
    k_xpart<<<dim3(RC / 64, 4), 256, 0, stream>>>(xcc, xpw, xpartb, RC, 512, 128);
    k_scanA<<<32 * NSC, 512, 0, stream>>>(xcc, xpartb, dtw, dtbias, Alog,
                                          hendb, sumdtb);
    k_scanB<<<32 * 512 * DS / 256, 256, 0, stream>>>(sumdtb, hendb, Alog, hstate, first);
    if (acc)
        k_scanC<1><<<32 * NSC, 512, 0, stream>>>(
            xcc, xpartb, dtw, dtbias, xzc, Alog, Dp, hendb,
            nullptr, nullptr, macc2, first);
    else
        k_scanC<0><<<32 * NSC, 512, 0, stream>>>(
            xcc, xpartb, dtw, dtbias, xzc, Alog, Dp, hendb,
            yh, yl, nullptr, 0);
}

extern "C" void kernel_launch(void* const* d_in, const int* in_sizes, int n_in,
                              void* d_out, int out_size, void* d_ws, size_t ws_size,
                              hipStream_t stream)
{
    const float* xseq = (const float*)d_in[0];
    const float* xst  = (const float*)d_in[1];
    const float* p1w  = (const float*)d_in[2];
    const float* p1b  = (const float*)d_in[3];
    const float* ln1g = (const float*)d_in[4];
    const float* ln1b = (const float*)d_in[5];
    const float* p2w  = (const float*)d_in[6];
    const float* p2b  = (const float*)d_in[7];
    const float* ln2g = (const float*)d_in[8];
    const float* ln2b = (const float*)d_in[9];
    const float* h1w  = (const float*)d_in[10];
    const float* h1b  = (const float*)d_in[11];
    const float* h2w  = (const float*)d_in[12];
    const float* h2b  = (const float*)d_in[13];
    const float* wo1  = (const float*)d_in[22];   // m1 out_w [256,512]
    const float* wo2  = (const float*)d_in[31];   // m2 out_w [256,512]

    float* ws = (float*)d_ws;
    float* xzc    = ws;                                  // RC*1024 f32
    float* xcc    = xzc  + (size_t)RC * 1024;            // RC*512
    // hend region: NSC*32*512*DS = RC*256 floats; x1 planes alias its head
    float* hendb  = xcc  + (size_t)RC * 512;
    u16*   x1h    = (u16*)hendb;                         // RC*256 u16
    u16*   x1l    = x1h + (size_t)RC * 256;              // RC*256 u16
    float* hend_end = hendb + (size_t)NSC * 32 * 512 * DS;
    u16*   yh     = (u16*)hend_end;                      // RC*512 u16
    u16*   yl     = yh + (size_t)RC * 512;               // RC*512 u16
    float* sumdtb = (float*)(yl + (size_t)RC * 512);     // NSC*32*512
    float* halo1  = sumdtb + NSC * 32 * 512;             // 3*32*512
    float* halo2  = halo1 + 3 * 32 * 512;
    float* hs1    = halo2 + 3 * 32 * 512;                // 32*512*16
    float* hs2    = hs1  + 32 * 512 * DS;
    float* macc2  = hs2  + 32 * 512 * DS;                // 32*NSC*512 (1 MB)
    float* mm     = macc2 + 32 * NSC * 512;              // 32*256
    u16*   wm1ih  = (u16*)(mm + 32 * 256);               // 1024*256 u16 each
    u16*   wm1il  = wm1ih + 262144;
    u16*   wm2ih  = wm1il + 262144;
    u16*   wm2il  = wm2ih + 262144;
    u16*   wch    = wm2il + 262144;                      // 256*512 u16 each
    u16*   wcl    = wch + 131072;
    float* xpartb = (float*)(wcl + 131072);              // 4*RC*48 f32
    size_t need = (size_t)((char*)(xpartb + 4 * (size_t)RC * 48) - (char*)ws);
    if (ws_size < need) return;   // tripwire: fail cleanly, don't fault

    // weight prep (2 launches total)
    k_wcvt2<<<2048, 256, 0, stream>>>(
        (const float*)d_in[14], (const float*)d_in[23],
        wm1ih, wm1il, wm2ih, wm2il);
    k_wcomb<<<512, 256, 0, stream>>>(p2w, wo1, wch, wcl);

    for (int c = 0; c < NCH; c++) {
        int t0 = c * CH;
        int save_halo = (c != NCH - 1);

        k_p1_ln<<<RC, 256, 0, stream>>>(xseq, p1w, p1b, ln1g, ln1b, x1h, x1l, t0);

        // mamba 1 core (params d_in[14..22]) -> y planes
        run_mamba_core(stream, x1h, x1l, d_in + 14, wm1ih, wm1il,
                       xzc, xcc, xpartb, yh, yl,
                       hendb, sumdtb, halo1, hs1, nullptr, 0, t0, save_halo);

        // fused out_proj1+p2 (y @ Wc^T + p2b) -> LN2
        k_gmfma<true><<<dim3(RC / 128, 256 / 128), 256, 0, stream>>>(
            yh, yl, 512, wch, wcl, p2b, xzc, 256, 512);
        k_ln<<<RC, 256, 0, stream>>>(xzc, ln2g, ln2b, x1h, x1l);

        // mamba 2 core (params d_in[23..31]); y accumulated into macc2,
        // out_proj folded into prehead
        run_mamba_core(stream, x1h, x1l, d_in + 23, wm2ih, wm2il,
                       xzc, xcc, xpartb, yh, yl,
                       hendb, sumdtb, halo2, hs2, macc2, 1, t0, save_halo);
    }

    k_prehead<<<NB, 256, 0, stream>>>(macc2, wo2, mm);
    k_head<<<NB, 128, 0, stream>>>(mm, xst, h1w, h1b, h2w, h2b, (float*)d_out);
}